// Round 6
// baseline (1011.127 us; speedup 1.0000x reference)
//
#include <hip/hip_runtime.h>

#define BATCH 512
#define SEQ   512
#define VOCAB 1000
#define EMB   100
#define UNITS 64
#define R     4   // batch rows per wave: independent chains hide each other's
                  // DS latency (r5 showed 1-row/wave leaves VALU 20%, DS ~35%)

typedef float v2f __attribute__((ext_vector_type(2)));
typedef float v4f __attribute__((ext_vector_type(4)));

// ---------------------------------------------------------------------------
// Kernel 1: P[v][u] = sum_d emb[v][d] * Wxh[d][u] + b[u]   (VOCAB x UNITS)
// ---------------------------------------------------------------------------
__global__ __launch_bounds__(64) void proj_kernel(
    const float* __restrict__ emb, const float* __restrict__ Wxh,
    const float* __restrict__ bias, float* __restrict__ P) {
  const int v = blockIdx.x;
  const int u = threadIdx.x;
  const float* e = emb + v * EMB;
  float acc = bias[u];
#pragma unroll 5
  for (int d = 0; d < EMB; ++d) acc += e[d] * Wxh[d * UNITS + u];
  P[v * UNITS + u] = acc;
}

// ---------------------------------------------------------------------------
// Kernel 2: sequential scan. One wave handles R=4 batch rows; lane j = unit j.
//   h[j] <- tanh(P[tok_t][j] + sum_i h[i]*Whh[i][j])
// h broadcast via LDS (r5: kills the readlane->fmac SGPR hazard chain, 871->
// 571 cyc/step). r6: 4 independent rows per wave share the wh2[] weights and
// interleave their DS/VALU streams so the ~570-cyc single-chain latency is
// amortized 4x. DS pipe (~64 ds_read_b128/step) becomes the binding resource
// at ~200 cyc/row.
// ---------------------------------------------------------------------------
__global__ __launch_bounds__(64)
__attribute__((amdgpu_waves_per_eu(1, 1)))
void scan_kernel(
    const int* __restrict__ tok, const float* __restrict__ P,
    const float* __restrict__ Whh, const float* __restrict__ Wout,
    const float* __restrict__ bout, float* __restrict__ out) {
  const int lane = threadIdx.x;
  const int row0 = blockIdx.x * R;

  __shared__ __align__(16) v4f hs4[R][UNITS / 4];  // per-row broadcast buffers

  // Whh columns for this lane as 32 packed pairs (shared by all R rows).
  v2f wh2[UNITS / 2];
#pragma unroll
  for (int k = 0; k < UNITS / 2; ++k) {
    float wx = Whh[(2 * k + 0) * UNITS + lane];
    float wy = Whh[(2 * k + 1) * UNITS + lane];
    asm volatile("" : "+v"(wx), "+v"(wy));
    wh2[k].x = wx;
    wh2[k].y = wy;
  }

  // Tokens for all R rows, pre-scaled by UNITS (saves per-step addr math).
  int tokv[R][SEQ / 64];
#pragma unroll
  for (int r = 0; r < R; ++r) {
    const int* trow = tok + (long)(row0 + r) * SEQ;
#pragma unroll
    for (int c = 0; c < SEQ / 64; ++c) {
      int t = trow[c * 64 + lane] * UNITS;
      asm volatile("" : "+v"(t));
      tokv[r][c] = t;
    }
  }

  // h_0 = 0 (single wave: same-wave LDS ops are in-order, no barriers).
#pragma unroll
  for (int r = 0; r < R; ++r) ((float*)hs4[r])[lane] = 0.f;

  // Prefetch P rows for t=0.
  float a[R];
#pragma unroll
  for (int r = 0; r < R; ++r) {
    int tk0 = __builtin_amdgcn_readlane(tokv[r][0], 0);
    a[r] = P[(long)tk0 + lane];
  }

#pragma unroll
  for (int c = 0; c < SEQ / 64; ++c) {
#pragma unroll 2
    for (int tt = 0; tt < 64; ++tt) {
      const int ntt = (tt + 1) & 63;
      float s[R];

#pragma unroll
      for (int r = 0; r < R; ++r) {
        float a_cur = a[r];
        // Prefetch next timestep's P row (redundant in-chunk load at tt=63;
        // the real cross-chunk prefetch happens after the tt loop).
        int tkn = __builtin_amdgcn_readlane(tokv[r][c], ntt);
        a[r] = P[(long)tkn + lane];

        // Broadcast-read this row's h (16x ds_read_b128, same-address =>
        // conflict-free) and accumulate with packed fp32 FMAs.
        v2f acc0 = {0.f, 0.f}, acc1 = {0.f, 0.f};
        v2f acc2 = {0.f, 0.f}, acc3 = {0.f, 0.f};
#pragma unroll
        for (int q = 0; q < UNITS / 4; ++q) {
          v4f hq = hs4[r][q];
          v2f lo; lo.x = hq.x; lo.y = hq.y;
          v2f hi; hi.x = hq.z; hi.y = hq.w;
          if (q & 1) {
            acc2 += lo * wh2[2 * q + 0];
            acc3 += hi * wh2[2 * q + 1];
          } else {
            acc0 += lo * wh2[2 * q + 0];
            acc1 += hi * wh2[2 * q + 1];
          }
        }
        v2f rr = (acc0 + acc1) + (acc2 + acc3);
        s[r] = (rr.x + rr.y) + a_cur;
      }

      // tanh + publish, per row (writes ordered after this step's reads by
      // the in-order DS pipe; next step's reads see them).
#pragma unroll
      for (int r = 0; r < R; ++r) {
        float e = __expf(2.f * s[r]);
        float h = 1.f - 2.f / (e + 1.f);
        ((float*)hs4[r])[lane] = h;
      }
    }
    if (c + 1 < SEQ / 64) {
#pragma unroll
      for (int r = 0; r < R; ++r) {
        int tkb = __builtin_amdgcn_readlane(tokv[r][c + 1], 0);
        a[r] = P[(long)tkb + lane];
      }
    }
  }

  // out[row] = sigmoid(sum_j h[j]*Wout[j] + bout), per row.
  float wo = Wout[lane];
  float bo = bout[0];
#pragma unroll
  for (int r = 0; r < R; ++r) {
    float p = ((float*)hs4[r])[lane] * wo;
#pragma unroll
    for (int off = 32; off > 0; off >>= 1) p += __shfl_xor(p, off);
    if (lane == 0) out[row0 + r] = 1.f / (1.f + __expf(-(p + bo)));
  }
}

extern "C" void kernel_launch(void* const* d_in, const int* in_sizes, int n_in,
                              void* d_out, int out_size, void* d_ws, size_t ws_size,
                              hipStream_t stream) {
  const int*   tok  = (const int*)  d_in[0];  // [BATCH, SEQ] int32
  const float* emb  = (const float*)d_in[1];  // [VOCAB, EMB]
  const float* Wxh  = (const float*)d_in[2];  // [EMB, UNITS]
  const float* Whh  = (const float*)d_in[3];  // [UNITS, UNITS]
  const float* bias = (const float*)d_in[4];  // [UNITS]
  const float* Wout = (const float*)d_in[5];  // [UNITS, 1]
  const float* bout = (const float*)d_in[6];  // [1]
  float* out = (float*)d_out;                 // [BATCH, 1] fp32

  float* P = (float*)d_ws;                    // VOCAB*UNITS fp32 = 256 KB

  proj_kernel<<<VOCAB, 64, 0, stream>>>(emb, Wxh, bias, P);
  scan_kernel<<<BATCH / R, 64, 0, stream>>>(tok, P, Whh, Wout, bout, out);
}

// Round 7
// 184.000 us; speedup vs baseline: 5.4953x; 5.4953x over previous
//
#include <hip/hip_runtime.h>

#define BATCH 512
#define SEQ   512
#define VOCAB 1000
#define EMB   100
#define UNITS 64

typedef float v2f __attribute__((ext_vector_type(2)));
typedef float v4f __attribute__((ext_vector_type(4)));

// ---------------------------------------------------------------------------
// Kernel 1: P[v][u] = sum_d emb[v][d] * Wxh[d][u] + b[u]   (VOCAB x UNITS)
// ---------------------------------------------------------------------------
__global__ __launch_bounds__(64) void proj_kernel(
    const float* __restrict__ emb, const float* __restrict__ Wxh,
    const float* __restrict__ bias, float* __restrict__ P) {
  const int v = blockIdx.x;
  const int u = threadIdx.x;
  const float* e = emb + v * EMB;
  float acc = bias[u];
#pragma unroll 5
  for (int d = 0; d < EMB; ++d) acc += e[d] * Wxh[d * UNITS + u];
  P[v * UNITS + u] = acc;
}

// ---------------------------------------------------------------------------
// Kernel 2: sequential scan, ONE wave per batch row (r6 lesson: wall time =
// 512 x single-wave chain; packing rows per wave only lengthens the step).
//   h[j] <- tanh(P[tok_t][j] + sum_i h[i]*Whh[i][j])
//
// Chain structure per step (the only thing that matters):
//   ds_write h -> 16x ds_read_b128 (BATCHED: hoisted into hq[16] so the DS
//   pipe streams them back-to-back and only the last read's latency is
//   exposed; r5 consumed per-read = 16 serial round trips = 571 cyc/step)
//   -> 32 pk_fma -> tree -> tanh -> publish.
// ---------------------------------------------------------------------------
__global__ __launch_bounds__(64)
__attribute__((amdgpu_waves_per_eu(1, 1)))
void scan_kernel(
    const int* __restrict__ tok, const float* __restrict__ P,
    const float* __restrict__ Whh, const float* __restrict__ Wout,
    const float* __restrict__ bout, float* __restrict__ out) {
  const int row  = blockIdx.x;
  const int lane = threadIdx.x;

  __shared__ __align__(16) v4f hs4[UNITS / 4];  // 64 floats, broadcast buffer
  float* hsf = (float*)hs4;

  // Whh columns for this lane as 32 packed pairs, pinned in VGPRs.
  v2f wh2[UNITS / 2];
#pragma unroll
  for (int k = 0; k < UNITS / 2; ++k) {
    float wx = Whh[(2 * k + 0) * UNITS + lane];
    float wy = Whh[(2 * k + 1) * UNITS + lane];
    asm volatile("" : "+v"(wx), "+v"(wy));
    wh2[k].x = wx;
    wh2[k].y = wy;
  }

  // All 512 tokens of this row, pre-scaled by UNITS (coalesced loads).
  int tokv[SEQ / 64];
  const int* trow = tok + (long)row * SEQ;
#pragma unroll
  for (int c = 0; c < SEQ / 64; ++c) {
    int t = trow[c * 64 + lane] * UNITS;
    asm volatile("" : "+v"(t));
    tokv[c] = t;
  }

  // h_0 = 0 (single wave: same-wave LDS ops are in-order, no barriers).
  hsf[lane] = 0.f;

  // Prefetch P row for t=0.
  int tk0 = __builtin_amdgcn_readlane(tokv[0], 0);
  float a = P[(long)tk0 + lane];

#pragma unroll
  for (int c = 0; c < SEQ / 64; ++c) {
#pragma unroll 2
    for (int tt = 0; tt < 64; ++tt) {
      float a_cur = a;
      // Prefetch next timestep's P row (consumed ~1 full step later; L2 hit
      // latency ~200 cyc is covered by the ~350-cyc step).
      int ntt = (tt + 1) & 63;
      int tkn = __builtin_amdgcn_readlane(tokv[c], ntt);
      a = P[(long)tkn + lane];

      // ---- Phase 1: issue ALL 16 broadcast reads back-to-back. ----
      v4f hq[UNITS / 4];
#pragma unroll
      for (int q = 0; q < UNITS / 4; ++q) hq[q] = hs4[q];

      // ---- Phase 2: consume. a_cur folded into acc0 init (saves a
      // chain-tail add). 4 accumulators, 8-deep pk_fma chains. ----
      v2f acc0, acc1 = {0.f, 0.f}, acc2 = {0.f, 0.f}, acc3 = {0.f, 0.f};
      acc0.x = a_cur; acc0.y = 0.f;
#pragma unroll
      for (int q = 0; q < UNITS / 4; ++q) {
        v2f lo; lo.x = hq[q].x; lo.y = hq[q].y;
        v2f hi; hi.x = hq[q].z; hi.y = hq[q].w;
        if (q & 1) {
          acc2 += lo * wh2[2 * q + 0];
          acc3 += hi * wh2[2 * q + 1];
        } else {
          acc0 += lo * wh2[2 * q + 0];
          acc1 += hi * wh2[2 * q + 1];
        }
      }
      v2f rr = (acc0 + acc1) + (acc2 + acc3);
      float s = rr.x + rr.y;

      // tanh(s) = 1 - 2/(exp(2s)+1)  (safe at both extremes)
      float e = __expf(2.f * s);
      float h = 1.f - 2.f / (e + 1.f);

      // Publish h for the next step (in-order DS pipe: next step's reads,
      // issued after this write, see the new value).
      hsf[lane] = h;
    }
    if (c + 1 < SEQ / 64) {
      int tkb = __builtin_amdgcn_readlane(tokv[c + 1], 0);
      a = P[(long)tkb + lane];
    }
  }

  // out[row] = sigmoid(sum_j h[j]*Wout[j] + bout)
  float p = hsf[lane] * Wout[lane];
#pragma unroll
  for (int off = 32; off > 0; off >>= 1) p += __shfl_xor(p, off);
  if (lane == 0) out[row] = 1.f / (1.f + __expf(-(p + bout[0])));
}

extern "C" void kernel_launch(void* const* d_in, const int* in_sizes, int n_in,
                              void* d_out, int out_size, void* d_ws, size_t ws_size,
                              hipStream_t stream) {
  const int*   tok  = (const int*)  d_in[0];  // [BATCH, SEQ] int32
  const float* emb  = (const float*)d_in[1];  // [VOCAB, EMB]
  const float* Wxh  = (const float*)d_in[2];  // [EMB, UNITS]
  const float* Whh  = (const float*)d_in[3];  // [UNITS, UNITS]
  const float* bias = (const float*)d_in[4];  // [UNITS]
  const float* Wout = (const float*)d_in[5];  // [UNITS, 1]
  const float* bout = (const float*)d_in[6];  // [1]
  float* out = (float*)d_out;                 // [BATCH, 1] fp32

  float* P = (float*)d_ws;                    // VOCAB*UNITS fp32 = 256 KB

  proj_kernel<<<VOCAB, 64, 0, stream>>>(emb, Wxh, bias, P);
  scan_kernel<<<BATCH, 64, 0, stream>>>(tok, P, Whh, Wout, bout, out);
}